// Round 13
// baseline (2897.616 us; speedup 1.0000x reference)
//
#include <hip/hip_runtime.h>
#include <cstdint>
#include <cstddef>

typedef __bf16 bf16;
typedef __bf16 bf16x8 __attribute__((ext_vector_type(8)));
typedef __bf16 bf16x4 __attribute__((ext_vector_type(4)));
typedef float f32x4 __attribute__((ext_vector_type(4)));
typedef unsigned u32x4 __attribute__((ext_vector_type(4)));

#define B_ 64
#define S_ 512
#define E_ 512
#define H_ 1024
#define C_ 20
#define EH 1536   // E+H
#define G4 4096   // 4*H

// ---- workspace layout (bytes) ----
static const size_t OFF_WCAT  = 0;              // bf16 [4096][1536] = 12,582,912
static const size_t OFF_BIAS4 = 12582912;       // f32  [4096]       = 16,384
static const size_t OFF_A0    = 12599296;       // bf16 [64][1024]   = 131,072
static const size_t OFF_A1    = 12730368;       // bf16 [64][1024]   = 131,072
static const size_t OFF_CST   = 12861440;       // f32  [64][1024]   = 262,144
static const size_t OFF_LOSS  = 13123584;       // f32  [64]         = 256
static const size_t OFF_BAR   = 13123840;       // u32  [4][64][4] wave-flags = 4,096
static const size_t OFF_GX    = 13127936;       // bf16 [TC*64][4096] = TC*524,288
static const size_t STATE_BYTES = OFF_GX - OFF_A0;   // 528,640 (zeroed each call)

__device__ inline float sigmoidf_(float x) { return 1.0f / (1.0f + __expf(-x)); }
__device__ inline float tanh_fast(float x) {
  float ax = fabsf(x);
  float e = __expf(-2.0f * ax);
  float t = (1.0f - e) / (1.0f + e);
  return copysignf(t, x);
}

// ---- zero a0/a1/cst/loss/flags (contiguous state region) ----
__global__ __launch_bounds__(256) void init_misc(uint4* st) {
  const int n = (int)(STATE_BYTES / 16);   // 33,040
  for (int idx = blockIdx.x * 256 + threadIdx.x; idx < n; idx += gridDim.x * 256)
    st[idx] = uint4{0u, 0u, 0u, 0u};
}

// ---- convert gate weights to bf16, rows r = h*4+g (h-major, gate minor) ----
__global__ __launch_bounds__(256) void convert_w(
    const float* __restrict__ Wf, const float* __restrict__ Wi,
    const float* __restrict__ Wc, const float* __restrict__ Wo,
    const float* __restrict__ bfp, const float* __restrict__ bip,
    const float* __restrict__ bcp, const float* __restrict__ bop,
    bf16* __restrict__ Wcat, float* __restrict__ bias4)
{
  const int total = G4 * (EH / 8);   // 786,432 chunks of 8
  for (int idx = blockIdx.x * 256 + threadIdx.x; idx < total; idx += gridDim.x * 256) {
    const int r = idx / 192;
    const int ck = idx - r * 192;
    const int g = r & 3, h = r >> 2;
    const float* W = (g == 0) ? Wf : (g == 1) ? Wi : (g == 2) ? Wc : Wo;
    const float* src = W + (size_t)h * EH + ck * 8;
    const float4 v0 = *(const float4*)src;
    const float4 v1 = *(const float4*)(src + 4);
    bf16x8 o;
    o[0] = (bf16)v0.x; o[1] = (bf16)v0.y; o[2] = (bf16)v0.z; o[3] = (bf16)v0.w;
    o[4] = (bf16)v1.x; o[5] = (bf16)v1.y; o[6] = (bf16)v1.z; o[7] = (bf16)v1.w;
    *(bf16x8*)(Wcat + (size_t)r * EH + ck * 8) = o;
    if (ck == 0) {
      const float* Bp = (g == 0) ? bfp : (g == 1) ? bip : (g == 2) ? bcp : bop;
      bias4[r] = Bp[h];
    }
  }
}

// ---- gx_chunk[ml][r] = sum_k emb[x[m]][k] * Wcat[r][k], K = 512 (x-part) ----
__global__ __launch_bounds__(256) void gemm_gx(
    const int* __restrict__ x, const float* __restrict__ emb,
    const bf16* __restrict__ Wcat, bf16* __restrict__ gx, int t0)
{
  __shared__ char As[16384];
  __shared__ char Bs[16384];
  const int t = threadIdx.x;
  const int lane = t & 63, wid = t >> 6;
  const int wm = wid >> 1, wn = wid & 1;
  const int bm = blockIdx.x >> 5;
  const int bn = blockIdx.x & 31;
  const int m0l = bm * 128, n0 = bn * 128;
  f32x4 acc[4][4] = {};
  const int srow = t >> 3, sc16 = t & 7;
  for (int k0 = 0; k0 < E_; k0 += 64) {
    __syncthreads();
    #pragma unroll
    for (int i = 0; i < 4; ++i) {
      const int row = i * 32 + srow;
      const int cs = sc16 ^ (row & 7);     // pre-swizzled source chunk
      const int m = t0 * 64 + m0l + row;
      const int tok = x[(m & 63) * S_ + (m >> 6)];
      const float* srcA = emb + (size_t)tok * E_ + k0 + cs * 8;
      const float4 a0v = *(const float4*)srcA;
      const float4 a1v = *(const float4*)(srcA + 4);
      bf16x8 oa;
      oa[0] = (bf16)a0v.x; oa[1] = (bf16)a0v.y; oa[2] = (bf16)a0v.z; oa[3] = (bf16)a0v.w;
      oa[4] = (bf16)a1v.x; oa[5] = (bf16)a1v.y; oa[6] = (bf16)a1v.z; oa[7] = (bf16)a1v.w;
      *(bf16x8*)(As + row * 128 + sc16 * 16) = oa;
      const uint4 vb = *(const uint4*)(Wcat + (size_t)(n0 + row) * EH + k0 + cs * 8);
      *(uint4*)(Bs + row * 128 + sc16 * 16) = vb;
    }
    __syncthreads();
    #pragma unroll
    for (int ks = 0; ks < 64; ks += 32) {
      const int kb = (ks + ((lane >> 4) * 8)) * 2;
      bf16x8 af[4], bfr[4];
      #pragma unroll
      for (int mt = 0; mt < 4; ++mt) {
        const int ra = wm * 64 + mt * 16 + (lane & 15);
        af[mt] = *(const bf16x8*)(As + ra * 128 + (kb ^ ((ra & 7) << 4)));
      }
      #pragma unroll
      for (int nt = 0; nt < 4; ++nt) {
        const int rb = wn * 64 + nt * 16 + (lane & 15);
        bfr[nt] = *(const bf16x8*)(Bs + rb * 128 + (kb ^ ((rb & 7) << 4)));
      }
      #pragma unroll
      for (int mt = 0; mt < 4; ++mt)
        #pragma unroll
        for (int nt = 0; nt < 4; ++nt)
          acc[mt][nt] = __builtin_amdgcn_mfma_f32_16x16x32_bf16(af[mt], bfr[nt], acc[mt][nt], 0, 0, 0);
    }
  }
  const int cb = (lane >> 4) * 4;
  #pragma unroll
  for (int mt = 0; mt < 4; ++mt) {
    #pragma unroll
    for (int r = 0; r < 4; ++r) {
      const int mrow = m0l + wm * 64 + mt * 16 + cb + r;   // chunk-local row
      bf16* dst = gx + (size_t)mrow * G4 + n0 + wn * 64 + (lane & 15);
      #pragma unroll
      for (int nt = 0; nt < 4; ++nt)
        dst[nt * 16] = (bf16)acc[mt][nt][r];
    }
  }
}

// ---- persistent LSTM recurrence over steps [t0, t0+tc) ----
// 256 WGs = 4 batch-groups (16 batches) x 64 hidden-slice WGs (16 h each).
// R13 = R5 protocol (proven 980us/chunk) + three individually-proven shavings:
//  * oct-pack publish (R8): one 16B sc0sc1 store per 8 h-units (8 stores/wave)
//  * per-wave flags after wave-local vmcnt(0) drain (R8): no trailing WG
//    barrier on the publish path; flags[grp][wg][wave], value step+1.
//  * parity accs (R9): exactly ONE __syncthreads per step; the accs barrier
//    also keeps sibling waves within 1 step of each other, preserving the
//    ring-depth-2 overwrite-safety induction.
// Consumer wave w (k-quarter w): lane l15 polls the 4 wave-flags of producer
// WG (w*16+l15) with one 16B sc0sc1 load (divergent-exit loop; wave
// reconverges when its whole quarter has published). Payload: 8 x 16B
// sc0sc1 loads, read exactly once. All sync ops sc0sc1 (MALL) per the
// R10/R12 lesson: sc0-only flag handoff deadlocks.
__global__ __launch_bounds__(256, 1) void lstm_rec(
    const bf16* __restrict__ Wcat, const float* __restrict__ bias4,
    const bf16* __restrict__ gx, bf16* __restrict__ a0,
    bf16* __restrict__ a1, float* __restrict__ cstg,
    unsigned* __restrict__ bar, int t0, int tc)
{
  __shared__ __align__(16) float accs[2][4][16][68];   // parity double-buffer
  const int t = threadIdx.x;
  const int lane = t & 63;
  const int w = t >> 6;                     // wave id = K-quarter
  const int bid = blockIdx.x;
  const int grp = bid & 3;                  // batch group (16 batches)
  const int hwg = bid >> 2;                 // 0..63 hidden slice
  const int h0 = hwg * 16;
  const int l15 = lane & 15;
  const int ksub = lane >> 4;               // 0..3
  const int kq8 = ksub * 8;

  // --- preload W B-fragments: 64 gate rows x my K-quarter (256 cols) ---
  bf16x8 wf[32];                            // static-indexed -> regs/AGPRs
  {
    const bf16* wbase = Wcat + (size_t)(h0 * 4 + l15) * EH + 512 + w * 256 + kq8;
    #pragma unroll
    for (int nt = 0; nt < 4; ++nt)
      #pragma unroll
      for (int i = 0; i < 8; ++i)
        wf[nt * 8 + i] = *(const bf16x8*)(wbase + (size_t)nt * 16 * EH + i * 32);
  }
  const int j   = t & 15;                   // hidden unit within slice
  const int blb = t >> 4;                   // batch within group
  const float4 bias = *(const float4*)(bias4 + (h0 + j) * 4);
  const int bg0 = grp * 16 + blb;
  float cst = cstg[(size_t)bg0 * H_ + h0 + j];
  unsigned* gflags = bar + grp * 256;       // [64 WG][4 wave]
  // consumer: lane l15 polls producer WG (w*16+l15)'s 4 wave-flags (16B)
  const unsigned* fquad = gflags + (w * 16 + l15) * 4;
  // producer: this wave's flag
  unsigned* const myflag = gflags + hwg * 4 + w;
  // payload base: batch (grp*16+l15), k = w*256 + kq8 + i*32
  const size_t pbase = (size_t)(grp * 16 + l15) * H_ + w * 256 + kq8;

  for (int s = 0; s < tc; ++s) {
    const int step = t0 + s;
    const bf16* aprev = (step & 1) ? a1 : a0;
    bf16* anext = (step & 1) ? a0 : a1;
    // gx for this step (plain cached load; drains under the poll's vmcnt)
    const bf16x4 g0 = *(const bf16x4*)(gx + (size_t)s * (B_ * G4) + (size_t)bg0 * G4 + (h0 + j) * 4);

    // ---- poll: one 16B sc0sc1 load of 4 wave-flags per iteration ----
    {
      const unsigned tgt = (unsigned)step;
      u32x4 fq;
      do {
        asm volatile("global_load_dwordx4 %0, %1, off sc0 sc1"
                     : "=v"(fq) : "v"(fquad) : "memory");
        asm volatile("s_waitcnt vmcnt(0)" ::: "memory");
        __builtin_amdgcn_sched_barrier(0);
      } while (fq.x < tgt || fq.y < tgt || fq.z < tgt || fq.w < tgt);
    }
    __builtin_amdgcn_sched_barrier(0);

    // ---- payload: 8 x 16B coherent loads, read exactly once ----
    u32x4 pay[8];
    #pragma unroll
    for (int i = 0; i < 8; ++i)
      asm volatile("global_load_dwordx4 %0, %1, off sc0 sc1"
                   : "=v"(pay[i]) : "v"(aprev + pbase + i * 32) : "memory");
    asm volatile("s_waitcnt vmcnt(0)" ::: "memory");
    __builtin_amdgcn_sched_barrier(0);

    // ---- MFMA over my K-quarter ----
    f32x4 pacc[4] = {};
    #pragma unroll
    for (int i = 0; i < 8; ++i) {
      const bf16x8 a8 = __builtin_bit_cast(bf16x8, pay[i]);
      #pragma unroll
      for (int nt = 0; nt < 4; ++nt)
        pacc[nt] = __builtin_amdgcn_mfma_f32_16x16x32_bf16(a8, wf[nt * 8 + i], pacc[nt], 0, 0, 0);
    }
    // ---- cross-wave K-reduction via parity LDS (single barrier/step) ----
    const int par = step & 1;
    {
      const int m0 = ksub * 4;
      #pragma unroll
      for (int nt = 0; nt < 4; ++nt)
        #pragma unroll
        for (int r = 0; r < 4; ++r)
          accs[par][w][m0 + r][nt * 16 + l15] = pacc[nt][r];
    }
    __syncthreads();
    const float4 q0 = *(const float4*)&accs[par][0][blb][j * 4];
    const float4 q1 = *(const float4*)&accs[par][1][blb][j * 4];
    const float4 q2 = *(const float4*)&accs[par][2][blb][j * 4];
    const float4 q3 = *(const float4*)&accs[par][3][blb][j * 4];
    float hv;
    {
      const float pf = q0.x + q1.x + q2.x + q3.x + (float)g0[0] + bias.x;
      const float pi = q0.y + q1.y + q2.y + q3.y + (float)g0[1] + bias.y;
      const float pc = q0.z + q1.z + q2.z + q3.z + (float)g0[2] + bias.z;
      const float po = q0.w + q1.w + q2.w + q3.w + (float)g0[3] + bias.w;
      const float fg = sigmoidf_(pf), ig = sigmoidf_(pi), og = sigmoidf_(po);
      cst = fg * cst + ig * tanh_fast(pc);
      hv = tanh_fast(cst) * og;
    }
    // ---- publish: oct-pack 8 bf16 -> one 16B sc0sc1 store (j%8==0) ----
    {
      const unsigned me  = (unsigned)__builtin_bit_cast(unsigned short, (bf16)hv);
      const unsigned pr  = me | (__shfl_down(me, 1) << 16);
      const unsigned pr2 = __shfl_down(pr, 2);
      const unsigned pr4 = __shfl_down(pr, 4);
      const unsigned pr24 = __shfl_down(pr2, 4);
      if ((j & 7) == 0) {
        u32x4 o; o.x = pr; o.y = pr2; o.z = pr4; o.w = pr24;
        asm volatile("global_store_dwordx4 %0, %1, off sc0 sc1"
                     :: "v"(anext + (size_t)bg0 * H_ + h0 + j), "v"(o) : "memory");
      }
    }
    // wave-local drain, then this wave's flag (no trailing WG barrier)
    asm volatile("s_waitcnt vmcnt(0)" ::: "memory");
    __builtin_amdgcn_sched_barrier(0);
    if (lane == 0) {
      const unsigned nf = (unsigned)(step + 1);
      asm volatile("global_store_dword %0, %1, off sc0 sc1"
                   :: "v"(myflag), "v"(nf) : "memory");
    }
    __builtin_amdgcn_sched_barrier(0);
  }
  cstg[(size_t)bg0 * H_ + h0 + j] = cst;
}

// ---- logits + per-batch loss ----
__global__ __launch_bounds__(256) void logits_loss(
    const bf16* __restrict__ afin, const float* __restrict__ Wv,
    const float* __restrict__ bv, const int* __restrict__ label,
    float* __restrict__ lossa)
{
  const int b = blockIdx.x;
  const int t = threadIdx.x;
  const int lane = t & 63, wid = t >> 6;
  const bf16x4 a4 = *(const bf16x4*)(afin + (size_t)b * H_ + t * 4);
  const float av0 = (float)a4[0], av1 = (float)a4[1], av2 = (float)a4[2], av3 = (float)a4[3];
  float part[C_];
  #pragma unroll
  for (int c = 0; c < C_; ++c) {
    const float4 w = *(const float4*)(Wv + (size_t)c * H_ + t * 4);
    part[c] = av0 * w.x + av1 * w.y + av2 * w.z + av3 * w.w;
  }
  #pragma unroll
  for (int off = 32; off > 0; off >>= 1) {
    #pragma unroll
    for (int c = 0; c < C_; ++c) part[c] += __shfl_down(part[c], off);
  }
  __shared__ float red[4][C_];
  __shared__ float lg[C_];
  if (lane == 0) {
    #pragma unroll
    for (int c = 0; c < C_; ++c) red[wid][c] = part[c];
  }
  __syncthreads();
  if (t < C_) lg[t] = red[0][t] + red[1][t] + red[2][t] + red[3][t] + bv[t];
  __syncthreads();
  if (t == 0) {
    float m = lg[0];
    for (int c = 1; c < C_; ++c) m = fmaxf(m, lg[c]);
    float se = 0.0f;
    for (int c = 0; c < C_; ++c) se += __expf(lg[c] - m);
    const float lse = logf(se) + m;
    lossa[b] = lse - lg[label[b]];
  }
}

__global__ __launch_bounds__(64) void loss_mean(const float* __restrict__ lossa,
                                                float* __restrict__ out) {
  const int t = threadIdx.x;
  float v = lossa[t];
  #pragma unroll
  for (int off = 32; off > 0; off >>= 1) v += __shfl_down(v, off);
  if (t == 0) out[0] = v * (1.0f / 64.0f);
}

extern "C" void kernel_launch(void* const* d_in, const int* in_sizes, int n_in,
                              void* d_out, int out_size, void* d_ws, size_t ws_size,
                              hipStream_t stream) {
  const int*   x     = (const int*)d_in[0];
  const int*   label = (const int*)d_in[1];
  const float* emb   = (const float*)d_in[2];
  const float* Wf    = (const float*)d_in[3];
  const float* bfp   = (const float*)d_in[4];
  const float* Wi    = (const float*)d_in[5];
  const float* bip   = (const float*)d_in[6];
  const float* Wc    = (const float*)d_in[7];
  const float* bcp   = (const float*)d_in[8];
  const float* Wo    = (const float*)d_in[9];
  const float* bop   = (const float*)d_in[10];
  const float* Wv    = (const float*)d_in[11];
  const float* bv    = (const float*)d_in[12];
  (void)in_sizes; (void)n_in; (void)out_size;

  // Pick the largest time-chunk TC whose gx buffer fits the workspace.
  int TC = 0;
  const size_t avail = (ws_size > OFF_GX) ? (ws_size - OFF_GX) : 0;
  const int cands[7] = {512, 256, 128, 64, 32, 16, 8};
  for (int i = 0; i < 7; ++i) {
    if ((size_t)cands[i] * 524288 <= avail) { TC = cands[i]; break; }
  }
  if (TC == 0) return;   // ws < ~17.6 MB — cannot run this design

  char* ws = (char*)d_ws;
  bf16*     Wcat  = (bf16*)(ws + OFF_WCAT);
  float*    bias4 = (float*)(ws + OFF_BIAS4);
  bf16*     a0    = (bf16*)(ws + OFF_A0);
  bf16*     a1    = (bf16*)(ws + OFF_A1);
  float*    cstg  = (float*)(ws + OFF_CST);
  float*    lossa = (float*)(ws + OFF_LOSS);
  unsigned* bar   = (unsigned*)(ws + OFF_BAR);
  bf16*     gx    = (bf16*)(ws + OFF_GX);

  init_misc<<<64, 256, 0, stream>>>((uint4*)(ws + OFF_A0));
  convert_w<<<1024, 256, 0, stream>>>(Wf, Wi, Wc, Wo, bfp, bip, bcp, bop, Wcat, bias4);
  const int nchunks = S_ / TC;
  for (int c = 0; c < nchunks; ++c) {
    const int t0 = c * TC;
    gemm_gx<<<(TC / 2) * 32, 256, 0, stream>>>(x, emb, Wcat, gx, t0);
    lstm_rec<<<256, 256, 0, stream>>>(Wcat, bias4, gx, a0, a1, cstg, bar, t0, TC);
  }
  // final state = h(511) in buffer (511+1)&1 = 0 -> a0
  logits_loss<<<64, 256, 0, stream>>>(a0, Wv, bv, label, lossa);
  loss_mean<<<1, 64, 0, stream>>>(lossa, (float*)d_out);
}

// Round 14
// 2061.352 us; speedup vs baseline: 1.4057x; 1.4057x over previous
//
#include <hip/hip_runtime.h>
#include <cstdint>
#include <cstddef>

typedef __bf16 bf16;
typedef __bf16 bf16x8 __attribute__((ext_vector_type(8)));
typedef __bf16 bf16x4 __attribute__((ext_vector_type(4)));
typedef float f32x4 __attribute__((ext_vector_type(4)));
typedef unsigned u32x4 __attribute__((ext_vector_type(4)));

#define B_ 64
#define S_ 512
#define E_ 512
#define H_ 1024
#define C_ 20
#define EH 1536   // E+H
#define G4 4096   // 4*H

// ---- workspace layout (bytes) ----
static const size_t OFF_WCAT  = 0;              // bf16 [4096][1536] = 12,582,912
static const size_t OFF_BIAS4 = 12582912;       // f32  [4096]       = 16,384
static const size_t OFF_A0    = 12599296;       // bf16 [64][1024]   = 131,072
static const size_t OFF_A1    = 12730368;       // bf16 [64][1024]   = 131,072
static const size_t OFF_CST   = 12861440;       // f32  [64][1024]   = 262,144
static const size_t OFF_LOSS  = 13123584;       // f32  [64]         = 256
static const size_t OFF_BAR   = 13123840;       // u32  [4][64] WG flags = 1,024
static const size_t OFF_GX    = 13127936;       // bf16 [TC*64][4096] = TC*524,288
static const size_t STATE_BYTES = OFF_GX - OFF_A0;   // 528,640 (zeroed each call)

__device__ inline float sigmoidf_(float x) { return 1.0f / (1.0f + __expf(-x)); }
__device__ inline float tanh_fast(float x) {
  float ax = fabsf(x);
  float e = __expf(-2.0f * ax);
  float t = (1.0f - e) / (1.0f + e);
  return copysignf(t, x);
}

// coherent 16B load: bypass L1/L2, read the MALL coherence point directly.
__device__ inline void load_coh16(u32x4* dst, const void* p) {
  asm volatile("global_load_dwordx4 %0, %1, off sc0 sc1"
               : "=v"(*dst) : "v"(p) : "memory");
}

// ---- zero a0/a1/cst/loss/flags (contiguous state region) ----
__global__ __launch_bounds__(256) void init_misc(uint4* st) {
  const int n = (int)(STATE_BYTES / 16);   // 33,040
  for (int idx = blockIdx.x * 256 + threadIdx.x; idx < n; idx += gridDim.x * 256)
    st[idx] = uint4{0u, 0u, 0u, 0u};
}

// ---- convert gate weights to bf16, rows r = h*4+g (h-major, gate minor) ----
__global__ __launch_bounds__(256) void convert_w(
    const float* __restrict__ Wf, const float* __restrict__ Wi,
    const float* __restrict__ Wc, const float* __restrict__ Wo,
    const float* __restrict__ bfp, const float* __restrict__ bip,
    const float* __restrict__ bcp, const float* __restrict__ bop,
    bf16* __restrict__ Wcat, float* __restrict__ bias4)
{
  const int total = G4 * (EH / 8);   // 786,432 chunks of 8
  for (int idx = blockIdx.x * 256 + threadIdx.x; idx < total; idx += gridDim.x * 256) {
    const int r = idx / 192;
    const int ck = idx - r * 192;
    const int g = r & 3, h = r >> 2;
    const float* W = (g == 0) ? Wf : (g == 1) ? Wi : (g == 2) ? Wc : Wo;
    const float* src = W + (size_t)h * EH + ck * 8;
    const float4 v0 = *(const float4*)src;
    const float4 v1 = *(const float4*)(src + 4);
    bf16x8 o;
    o[0] = (bf16)v0.x; o[1] = (bf16)v0.y; o[2] = (bf16)v0.z; o[3] = (bf16)v0.w;
    o[4] = (bf16)v1.x; o[5] = (bf16)v1.y; o[6] = (bf16)v1.z; o[7] = (bf16)v1.w;
    *(bf16x8*)(Wcat + (size_t)r * EH + ck * 8) = o;
    if (ck == 0) {
      const float* Bp = (g == 0) ? bfp : (g == 1) ? bip : (g == 2) ? bcp : bop;
      bias4[r] = Bp[h];
    }
  }
}

// ---- gx_chunk[ml][r] = sum_k emb[x[m]][k] * Wcat[r][k], K = 512 (x-part) ----
__global__ __launch_bounds__(256) void gemm_gx(
    const int* __restrict__ x, const float* __restrict__ emb,
    const bf16* __restrict__ Wcat, bf16* __restrict__ gx, int t0)
{
  __shared__ char As[16384];
  __shared__ char Bs[16384];
  const int t = threadIdx.x;
  const int lane = t & 63, wid = t >> 6;
  const int wm = wid >> 1, wn = wid & 1;
  const int bm = blockIdx.x >> 5;
  const int bn = blockIdx.x & 31;
  const int m0l = bm * 128, n0 = bn * 128;
  f32x4 acc[4][4] = {};
  const int srow = t >> 3, sc16 = t & 7;
  for (int k0 = 0; k0 < E_; k0 += 64) {
    __syncthreads();
    #pragma unroll
    for (int i = 0; i < 4; ++i) {
      const int row = i * 32 + srow;
      const int cs = sc16 ^ (row & 7);     // pre-swizzled source chunk
      const int m = t0 * 64 + m0l + row;
      const int tok = x[(m & 63) * S_ + (m >> 6)];
      const float* srcA = emb + (size_t)tok * E_ + k0 + cs * 8;
      const float4 a0v = *(const float4*)srcA;
      const float4 a1v = *(const float4*)(srcA + 4);
      bf16x8 oa;
      oa[0] = (bf16)a0v.x; oa[1] = (bf16)a0v.y; oa[2] = (bf16)a0v.z; oa[3] = (bf16)a0v.w;
      oa[4] = (bf16)a1v.x; oa[5] = (bf16)a1v.y; oa[6] = (bf16)a1v.z; oa[7] = (bf16)a1v.w;
      *(bf16x8*)(As + row * 128 + sc16 * 16) = oa;
      const uint4 vb = *(const uint4*)(Wcat + (size_t)(n0 + row) * EH + k0 + cs * 8);
      *(uint4*)(Bs + row * 128 + sc16 * 16) = vb;
    }
    __syncthreads();
    #pragma unroll
    for (int ks = 0; ks < 64; ks += 32) {
      const int kb = (ks + ((lane >> 4) * 8)) * 2;
      bf16x8 af[4], bfr[4];
      #pragma unroll
      for (int mt = 0; mt < 4; ++mt) {
        const int ra = wm * 64 + mt * 16 + (lane & 15);
        af[mt] = *(const bf16x8*)(As + ra * 128 + (kb ^ ((ra & 7) << 4)));
      }
      #pragma unroll
      for (int nt = 0; nt < 4; ++nt) {
        const int rb = wn * 64 + nt * 16 + (lane & 15);
        bfr[nt] = *(const bf16x8*)(Bs + rb * 128 + (kb ^ ((rb & 7) << 4)));
      }
      #pragma unroll
      for (int mt = 0; mt < 4; ++mt)
        #pragma unroll
        for (int nt = 0; nt < 4; ++nt)
          acc[mt][nt] = __builtin_amdgcn_mfma_f32_16x16x32_bf16(af[mt], bfr[nt], acc[mt][nt], 0, 0, 0);
    }
  }
  const int cb = (lane >> 4) * 4;
  #pragma unroll
  for (int mt = 0; mt < 4; ++mt) {
    #pragma unroll
    for (int r = 0; r < 4; ++r) {
      const int mrow = m0l + wm * 64 + mt * 16 + cb + r;   // chunk-local row
      bf16* dst = gx + (size_t)mrow * G4 + n0 + wn * 64 + (lane & 15);
      #pragma unroll
      for (int nt = 0; nt < 4; ++nt)
        dst[nt * 16] = (bf16)acc[mt][nt][r];
    }
  }
}

// ---- persistent LSTM recurrence over steps [t0, t0+tc) ----
// 256 WGs = 4 batch-groups (16 batches) x 64 hidden-slice WGs (16 h each).
// R14 == R5 verbatim (empirical optimum of 9 protocol variants):
//  * W B-fragments in registers (wave = K-quarter), no LDS on critical path.
//  * Publish: 4B packed write-through agent stores; __syncthreads drains;
//    single per-WG flag stored by t0 (MALL scope — sc0-only handoff hangs).
//  * Consumer: per-lane single-dword poll of its quarter's 16 producer flags
//    (lane l15 polls WG w*16+l15; 4 lanes share a flag); payload 8x16B
//    coherent loads read exactly once.
//  * accs[4][16][68] LDS reduce with two barriers (measured-fastest form).
__global__ __launch_bounds__(256, 1) void lstm_rec(
    const bf16* __restrict__ Wcat, const float* __restrict__ bias4,
    const bf16* __restrict__ gx, bf16* __restrict__ a0,
    bf16* __restrict__ a1, float* __restrict__ cstg,
    unsigned* __restrict__ bar, int t0, int tc)
{
  __shared__ float accs[4][16][68];
  const int t = threadIdx.x;
  const int lane = t & 63;
  const int w = t >> 6;                     // wave id = K-quarter
  const int bid = blockIdx.x;
  const int grp = bid & 3;                  // batch group (16 batches)
  const int hwg = bid >> 2;                 // 0..63 hidden slice
  const int h0 = hwg * 16;
  const int l15 = lane & 15;
  const int kq = (lane >> 4) * 8;           // k sub-offset within a 32-chunk

  // --- preload W B-fragments: 64 gate rows x my K-quarter (256 cols) ---
  bf16x8 wf[32];                            // [nt*8 + i], static-indexed
  {
    const bf16* wbase = Wcat + (size_t)(h0 * 4 + l15) * EH + 512 + w * 256 + kq;
    #pragma unroll
    for (int nt = 0; nt < 4; ++nt)
      #pragma unroll
      for (int i = 0; i < 8; ++i)
        wf[nt * 8 + i] = *(const bf16x8*)(wbase + (size_t)nt * 16 * EH + i * 32);
  }
  const int j   = t & 15;                   // hidden unit within slice
  const int blb = t >> 4;                   // batch within group (reduce phase)
  const float4 bias = *(const float4*)(bias4 + (h0 + j) * 4);
  const int bg0 = grp * 16 + blb;
  float cst = cstg[(size_t)bg0 * H_ + h0 + j];
  unsigned* flags = bar + grp * 64;         // 64 per-WG flag words
  unsigned* myflag = flags + w * 16 + l15;  // this lane's producer flag
  // payload base: batch (grp*16+l15), k = w*256 + kq + i*32
  const size_t pbase = (size_t)(grp * 16 + l15) * H_ + w * 256 + kq;

  for (int s = 0; s < tc; ++s) {
    const int step = t0 + s;
    const bf16* aprev = (step & 1) ? a1 : a0;
    bf16* anext = (step & 1) ? a0 : a1;
    // gx for this step: chunk-static, load BEFORE the poll (overlapped)
    const bf16* gxrow = gx + (size_t)s * (B_ * G4);
    const bf16x4 g0 = *(const bf16x4*)(gxrow + (size_t)bg0 * G4 + (h0 + j) * 4);
    // wave-level poll: only my K-quarter's 16 producers must have published
    {
      unsigned v;
      do {
        v = __hip_atomic_load(myflag, __ATOMIC_RELAXED, __HIP_MEMORY_SCOPE_AGENT);
      } while (v < (unsigned)step);
    }
    __builtin_amdgcn_sched_barrier(0);
    // A-fragments straight from MALL: lane = batch l15, cols quarter+kq
    const bf16* abase = aprev + pbase;
    u32x4 af[8];
    #pragma unroll
    for (int i = 0; i < 8; ++i) load_coh16(&af[i], abase + i * 32);
    asm volatile("s_waitcnt vmcnt(0)" ::: "memory");
    __builtin_amdgcn_sched_barrier(0);
    f32x4 pacc[4] = {};
    #pragma unroll
    for (int i = 0; i < 8; ++i) {
      const bf16x8 a8 = __builtin_bit_cast(bf16x8, af[i]);
      #pragma unroll
      for (int nt = 0; nt < 4; ++nt)
        pacc[nt] = __builtin_amdgcn_mfma_f32_16x16x32_bf16(a8, wf[nt * 8 + i], pacc[nt], 0, 0, 0);
    }
    __syncthreads();   // WAR: all waves done reading prev step's accs
    {
      const int m0 = (lane >> 4) * 4;
      #pragma unroll
      for (int nt = 0; nt < 4; ++nt)
        #pragma unroll
        for (int r = 0; r < 4; ++r)
          accs[w][m0 + r][nt * 16 + l15] = pacc[nt][r];
    }
    __syncthreads();
    // reduce the 4 K-partials for (batch blb, h-unit j): 4 gate pre-acts
    const float4 q0 = *(const float4*)&accs[0][blb][j * 4];
    const float4 q1 = *(const float4*)&accs[1][blb][j * 4];
    const float4 q2 = *(const float4*)&accs[2][blb][j * 4];
    const float4 q3 = *(const float4*)&accs[3][blb][j * 4];
    float hv;
    {
      const float pf = q0.x + q1.x + q2.x + q3.x + (float)g0[0] + bias.x;
      const float pi = q0.y + q1.y + q2.y + q3.y + (float)g0[1] + bias.y;
      const float pc = q0.z + q1.z + q2.z + q3.z + (float)g0[2] + bias.z;
      const float po = q0.w + q1.w + q2.w + q3.w + (float)g0[3] + bias.w;
      const float fg = sigmoidf_(pf), ig = sigmoidf_(pi), og = sigmoidf_(po);
      cst = fg * cst + ig * tanh_fast(pc);
      hv = tanh_fast(cst) * og;
    }
    // publish: pack 2 bf16 per dword, write-through agent store
    {
      const unsigned u0 = (unsigned)__builtin_bit_cast(unsigned short, (bf16)hv);
      const unsigned n0 = __shfl_down(u0, 1);
      if ((j & 1) == 0) {
        unsigned* an = (unsigned*)anext;
        __hip_atomic_store(an + ((size_t)bg0 * H_ + h0 + j) / 2, u0 | (n0 << 16),
                           __ATOMIC_RELAXED, __HIP_MEMORY_SCOPE_AGENT);
      }
    }
    __syncthreads();   // drains all threads' stores (vmcnt 0) -> all at MALL
    if (t == 0) {
      __hip_atomic_store(flags + hwg, (unsigned)(step + 1),
                         __ATOMIC_RELAXED, __HIP_MEMORY_SCOPE_AGENT);
    }
  }
  cstg[(size_t)bg0 * H_ + h0 + j] = cst;
}

// ---- logits + per-batch loss ----
__global__ __launch_bounds__(256) void logits_loss(
    const bf16* __restrict__ afin, const float* __restrict__ Wv,
    const float* __restrict__ bv, const int* __restrict__ label,
    float* __restrict__ lossa)
{
  const int b = blockIdx.x;
  const int t = threadIdx.x;
  const int lane = t & 63, wid = t >> 6;
  const bf16x4 a4 = *(const bf16x4*)(afin + (size_t)b * H_ + t * 4);
  const float av0 = (float)a4[0], av1 = (float)a4[1], av2 = (float)a4[2], av3 = (float)a4[3];
  float part[C_];
  #pragma unroll
  for (int c = 0; c < C_; ++c) {
    const float4 w = *(const float4*)(Wv + (size_t)c * H_ + t * 4);
    part[c] = av0 * w.x + av1 * w.y + av2 * w.z + av3 * w.w;
  }
  #pragma unroll
  for (int off = 32; off > 0; off >>= 1) {
    #pragma unroll
    for (int c = 0; c < C_; ++c) part[c] += __shfl_down(part[c], off);
  }
  __shared__ float red[4][C_];
  __shared__ float lg[C_];
  if (lane == 0) {
    #pragma unroll
    for (int c = 0; c < C_; ++c) red[wid][c] = part[c];
  }
  __syncthreads();
  if (t < C_) lg[t] = red[0][t] + red[1][t] + red[2][t] + red[3][t] + bv[t];
  __syncthreads();
  if (t == 0) {
    float m = lg[0];
    for (int c = 1; c < C_; ++c) m = fmaxf(m, lg[c]);
    float se = 0.0f;
    for (int c = 0; c < C_; ++c) se += __expf(lg[c] - m);
    const float lse = logf(se) + m;
    lossa[b] = lse - lg[label[b]];
  }
}

__global__ __launch_bounds__(64) void loss_mean(const float* __restrict__ lossa,
                                                float* __restrict__ out) {
  const int t = threadIdx.x;
  float v = lossa[t];
  #pragma unroll
  for (int off = 32; off > 0; off >>= 1) v += __shfl_down(v, off);
  if (t == 0) out[0] = v * (1.0f / 64.0f);
}

extern "C" void kernel_launch(void* const* d_in, const int* in_sizes, int n_in,
                              void* d_out, int out_size, void* d_ws, size_t ws_size,
                              hipStream_t stream) {
  const int*   x     = (const int*)d_in[0];
  const int*   label = (const int*)d_in[1];
  const float* emb   = (const float*)d_in[2];
  const float* Wf    = (const float*)d_in[3];
  const float* bfp   = (const float*)d_in[4];
  const float* Wi    = (const float*)d_in[5];
  const float* bip   = (const float*)d_in[6];
  const float* Wc    = (const float*)d_in[7];
  const float* bcp   = (const float*)d_in[8];
  const float* Wo    = (const float*)d_in[9];
  const float* bop   = (const float*)d_in[10];
  const float* Wv    = (const float*)d_in[11];
  const float* bv    = (const float*)d_in[12];
  (void)in_sizes; (void)n_in; (void)out_size;

  // Pick the largest time-chunk TC whose gx buffer fits the workspace.
  int TC = 0;
  const size_t avail = (ws_size > OFF_GX) ? (ws_size - OFF_GX) : 0;
  const int cands[7] = {512, 256, 128, 64, 32, 16, 8};
  for (int i = 0; i < 7; ++i) {
    if ((size_t)cands[i] * 524288 <= avail) { TC = cands[i]; break; }
  }
  if (TC == 0) return;   // ws < ~17.6 MB — cannot run this design

  char* ws = (char*)d_ws;
  bf16*     Wcat  = (bf16*)(ws + OFF_WCAT);
  float*    bias4 = (float*)(ws + OFF_BIAS4);
  bf16*     a0    = (bf16*)(ws + OFF_A0);
  bf16*     a1    = (bf16*)(ws + OFF_A1);
  float*    cstg  = (float*)(ws + OFF_CST);
  float*    lossa = (float*)(ws + OFF_LOSS);
  unsigned* bar   = (unsigned*)(ws + OFF_BAR);
  bf16*     gx    = (bf16*)(ws + OFF_GX);

  init_misc<<<64, 256, 0, stream>>>((uint4*)(ws + OFF_A0));
  convert_w<<<1024, 256, 0, stream>>>(Wf, Wi, Wc, Wo, bfp, bip, bcp, bop, Wcat, bias4);
  const int nchunks = S_ / TC;
  for (int c = 0; c < nchunks; ++c) {
    const int t0 = c * TC;
    gemm_gx<<<(TC / 2) * 32, 256, 0, stream>>>(x, emb, Wcat, gx, t0);
    lstm_rec<<<256, 256, 0, stream>>>(Wcat, bias4, gx, a0, a1, cstg, bar, t0, TC);
  }
  // final state = h(511) in buffer (511+1)&1 = 0 -> a0
  logits_loss<<<64, 256, 0, stream>>>(a0, Wv, bv, label, lossa);
  loss_mean<<<1, 64, 0, stream>>>(lossa, (float*)d_out);
}